// Round 2
// 28991.397 us; speedup vs baseline: 1.7660x; 1.7660x over previous
//
#include <hip/hip_runtime.h>
#include <hip/hip_bf16.h>

// GRU decoder, B=64, T=512, IN=512, H=1024, 2 layers.
// Persistent kernel, 256 WGs x 256 threads, dataflow sync via per-mh counters.
// Weights register-resident (fence/L2-inval immune). 64KB STATIC LDS, two 32KB
// buffers, K in 512-elem chunks, double-buffered global_load_lds staging from
// pre-swizzled bf16 rings. Biases hoisted. No dynamic LDS, no attr calls.

typedef __attribute__((ext_vector_type(8))) short short8;
typedef __attribute__((ext_vector_type(4))) float floatx4;

__device__ __forceinline__ float b2f(unsigned short u) {
  union { unsigned int i; float f; } v; v.i = ((unsigned int)u) << 16; return v.f;
}
__device__ __forceinline__ unsigned short f2b(float f) {
  unsigned int xi = __float_as_uint(f);
  return (unsigned short)((xi + 0x7fffu + ((xi >> 16) & 1u)) >> 16);  // RNE
}
__device__ __forceinline__ short8 cvt8(const float* __restrict__ p) {
  float4 a = *(const float4*)p;
  float4 b = *(const float4*)(p + 4);
  short8 v;
  v[0] = (short)f2b(a.x); v[1] = (short)f2b(a.y);
  v[2] = (short)f2b(a.z); v[3] = (short)f2b(a.w);
  v[4] = (short)f2b(b.x); v[5] = (short)f2b(b.y);
  v[6] = (short)f2b(b.z); v[7] = (short)f2b(b.w);
  return v;
}
__device__ __forceinline__ short8 ld8(const void* base, size_t e, bool f32) {
  return f32 ? cvt8((const float*)base + e)
             : *(const short8*)((const unsigned short*)base + e);
}
__device__ __forceinline__ float lds1(const void* base, size_t e, bool f32) {
  return f32 ? ((const float*)base)[e] : b2f(((const unsigned short*)base)[e]);
}
// async global->LDS, 16B/lane; LDS dest = wave-uniform base + lane*16 (linear)
typedef const __attribute__((address_space(1))) void* gas1_t;
typedef __attribute__((address_space(3))) void* las3_t;
__device__ __forceinline__ void glds16(const void* g, void* l) {
  __builtin_amdgcn_global_load_lds((gas1_t)g, (las3_t)l, 16, 0, 0);
}

// Mode detect: weights ~U(-0.031,0.031). If data is bf16, every u32's LOW
// half-word is a weight (|v|<=0.031). If fp32, low 16 bits are random mantissa.
__global__ void detect_mode(const unsigned int* __restrict__ w, int* __restrict__ flag) {
  int bad = 0;
  #pragma unroll
  for (int j = 0; j < 4; ++j) {
    unsigned int u = w[threadIdx.x * 4 + j];
    float f = b2f((unsigned short)(u & 0xFFFFu));
    if (!(fabsf(f) <= 1.0f)) bad = 1;
  }
  if (bad) atomicOr(flag, 1);
}

__global__ __launch_bounds__(256)
void cvt_w(const float* __restrict__ src, unsigned short* __restrict__ dst, int n,
           const int* __restrict__ flag) {
  if (*flag == 0) return;                 // bf16 mode: no staging
  int stride = gridDim.x * 256 * 4;
  for (int i = (blockIdx.x * 256 + threadIdx.x) * 4; i + 3 < n; i += stride) {
    float4 f = *(const float4*)(src + i);
    ushort4 u;
    u.x = f2b(f.x); u.y = f2b(f.y); u.z = f2b(f.z); u.w = f2b(f.w);
    *(ushort4*)(dst + i) = u;
  }
}

__device__ __forceinline__ void wait2(int* c0, int t0, int* c1, int t1) {
  if (threadIdx.x == 0) {
    while (__hip_atomic_load(c0, __ATOMIC_ACQUIRE, __HIP_MEMORY_SCOPE_AGENT) < t0)
      __builtin_amdgcn_s_sleep(2);
    if (c1)
      while (__hip_atomic_load(c1, __ATOMIC_ACQUIRE, __HIP_MEMORY_SCOPE_AGENT) < t1)
        __builtin_amdgcn_s_sleep(2);
  }
  __syncthreads();
  __threadfence();
}

// stage 32 rows x 512 elems via registers (fp32-cvt or bf16 copy), swizzled.
// src element index = base + r*stride + col8*8 ; LDS row stride 1024 B.
__device__ __forceinline__ void stage_reg512(char* __restrict__ buf, const void* __restrict__ src,
                                             size_t base, size_t stride, bool f32, int tid) {
  #pragma unroll
  for (int i = 0; i < 8; ++i) {
    int g = tid + i * 256;            // 0..2047
    int r = g >> 6, col8 = g & 63;
    short8 v = ld8(src, base + (size_t)r * stride + (size_t)(col8 * 8), f32);
    *(short8*)(buf + r * 1024 + ((col8 * 16) ^ ((r & 7) << 4))) = v;
  }
}

// stage 32 rows x 512 elems via global_load_lds from PRE-SWIZZLED ring half.
// src points at ringslot + col-offset; rows b = mh*32 + r. Linear copy; the
// ring's element permutation (j ^ ((b&7)<<3)) equals the LDS read swizzle.
__device__ __forceinline__ void stage_ring512(char* __restrict__ buf,
                                              const unsigned short* __restrict__ src,
                                              int mh, int wave, int lane) {
  #pragma unroll
  for (int rr = 0; rr < 8; ++rr) {
    int r = wave * 8 + rr;
    glds16(src + (size_t)(mh * 32 + r) * 1024 + lane * 8, buf + r * 1024);
  }
}

// 16 MFMA steps over one 512-elem chunk; A rows ln / 16+ln, swizzled reads.
#define MFMA_CHUNK(CBASE, BUF, ACC0, ACC1)                                        \
  do { _Pragma("unroll")                                                          \
    for (int s = 0; s < 16; ++s) {                                                \
      int off = (s * 64 + lq * 16) ^ swz;                                         \
      short8 a0 = *(const short8*)((BUF) + ln * 1024 + off);                      \
      short8 a1 = *(const short8*)((BUF) + (16 + ln) * 1024 + off);               \
      ACC0 = __builtin_amdgcn_mfma_f32_16x16x32_bf16(a0, wreg[(CBASE) + s], ACC0, 0, 0, 0); \
      ACC1 = __builtin_amdgcn_mfma_f32_16x16x32_bf16(a1, wreg[(CBASE) + s], ACC1, 0, 0, 0); \
    } } while (0)

__global__ __launch_bounds__(256, 1)
void gru_persist(const void* __restrict__ x,     // [64,512,512]
                 const void* __restrict__ ench,  // [64,1024]
                 const void* __restrict__ Wih0, const void* __restrict__ Whh0,
                 const void* __restrict__ bih0, const void* __restrict__ bhh0,
                 const void* __restrict__ Wih1, const void* __restrict__ Whh1,
                 const void* __restrict__ bih1, const void* __restrict__ bhh1,
                 void* __restrict__ out,         // [64,512,1024] + [64,1024]
                 const unsigned short* __restrict__ wih0s,  // staged bf16 or null
                 const unsigned short* __restrict__ whh0s,
                 const unsigned short* __restrict__ wih1s,
                 const unsigned short* __restrict__ whh1s,
                 int* __restrict__ h0cnt,        // per-mh @ +0,+64B
                 int* __restrict__ h1cnt,        // per-mh @ +0,+64B
                 const int* __restrict__ flag,
                 unsigned short* __restrict__ h0ring,   // 4 x 64x1024 bf16, swizzled
                 unsigned short* __restrict__ h1ring)   // 4 x 64x1024 bf16, swizzled
{
  // 64 KB static: buf0 = rows*1024B @0, buf1 @32768. FB (8KB gate exchange)
  // aliases buf0 bytes 0..8191 — written only after ALL chunk MFMAs complete.
  __shared__ __align__(16) char smem[65536];
  char* buf0 = smem;
  char* buf1 = smem + 32768;
  float* FB  = (float*)smem;

  const bool f32 = (__hip_atomic_load((int*)flag, __ATOMIC_RELAXED,
                                      __HIP_MEMORY_SCOPE_AGENT) != 0);
  const bool staged = f32 && (wih0s != nullptr);

  const int tid  = threadIdx.x;
  const int wave = tid >> 6;
  const int lane = tid & 63;
  const int ln   = lane & 15;             // A-row / B-col within 16-tile
  const int lq   = lane >> 4;             // k-quad

  const int wg  = blockIdx.x;
  const bool l0 = (wg < 128);
  const int lw  = l0 ? wg : (wg - 128);
  const int mh  = lw & 1;                 // batch rows 32*mh..+31
  const int jt  = lw >> 1;                // output cols 16*jt..+15

  int* myh0 = h0cnt + mh * 16;            // 64B-separated per-mh counters
  int* myh1 = h1cnt + mh * 16;

  // weight sources
  const void* WI; const void* WH; bool wf32;
  if (staged) { WI = l0 ? (const void*)wih0s : (const void*)wih1s;
                WH = l0 ? (const void*)whh0s : (const void*)whh1s; wf32 = false; }
  else        { WI = l0 ? Wih0 : Wih1; WH = l0 ? Whh0 : Whh1; wf32 = f32; }
  const int KWI = l0 ? 512 : 1024;
  size_t wi_off = 0, wh_off = 0;
  if (wave < 3) {
    int row = wave * 1024 + jt * 16 + ln;   // gate = wave
    wi_off = (size_t)row * KWI;
    wh_off = (size_t)row * 1024;
  }

  // ---- preload ALL weights into registers (fence/L2-inval immune) ----
  // per compute wave: 16 cols x K(1536|2048) bf16 = 48|64 short8 = 192|256 VGPR
  short8 wreg[64];
  if (wave < 3) {
    if (l0) {
      #pragma unroll
      for (int c = 0; c < 48; ++c) {
        int k = c * 32 + lq * 8;
        wreg[c] = (c < 16) ? ld8(WI, wi_off + k, wf32)
                           : ld8(WH, wh_off + (k - 512), wf32);
      }
    } else {
      #pragma unroll
      for (int c = 0; c < 64; ++c) {
        int k = c * 32 + lq * 8;
        wreg[c] = (c < 32) ? ld8(WI, wi_off + k, wf32)
                           : ld8(WH, wh_off + (k - 1024), wf32);
      }
    }
  }

  // ---- hoist biases ----
  const int c_   = tid & 15;
  const int rb   = tid >> 4;              // 0..15
  const int jcol = jt * 16 + c_;
  const void* bi = l0 ? bih0 : bih1;
  const void* bh = l0 ? bhh0 : bhh1;
  const float bir  = lds1(bi, jcol, f32),        bhr = lds1(bh, jcol, f32);
  const float biz  = lds1(bi, 1024 + jcol, f32), bhz = lds1(bh, 1024 + jcol, f32);
  const float bin_ = lds1(bi, 2048 + jcol, f32), bhn = lds1(bh, 2048 + jcol, f32);

  const int swz = (ln & 7) << 4;          // byte swizzle for MFMA ds_reads
  const size_t ebase = (size_t)mh * 32 * 1024;   // ench row base (elems)

  for (int p = 0; p <= 512; ++p) {
    if (l0 && p >= 512) break;
    if (!l0 && p == 0) continue;

    floatx4 accR0 = {0,0,0,0}, accR1 = {0,0,0,0};  // wave0:r wave1:z wave2:n_i
    floatx4 accS0 = {0,0,0,0}, accS1 = {0,0,0,0};  // wave2:n_h

    if (l0) {
      // chunk0 = x (k 0..511): reg-path stage BEFORE the wait (overlaps spin)
      stage_reg512(buf0, x, (size_t)mh * 32 * 262144 + (size_t)p * 512, 262144, f32, tid);
      if (p >= 1) wait2(myh0, 64 * p, (p >= 4) ? myh1 : nullptr, 64 * (p - 3));
      else        __syncthreads();
      const unsigned short* h0s = h0ring + (size_t)((p - 1) & 3) * 65536;
      // chunk1 = h0prev[0..511] (k 512..1023)
      if (p == 0) stage_reg512(buf1, ench, ebase, 1024, f32, tid);
      else        stage_ring512(buf1, h0s, mh, wave, lane);
      if (wave < 3) MFMA_CHUNK(0, buf0, accR0, accR1);
      __syncthreads();
      // chunk2 = h0prev[512..1023] (k 1024..1535)
      if (p == 0) stage_reg512(buf0, ench, ebase + 512, 1024, f32, tid);
      else        stage_ring512(buf0, h0s + 512, mh, wave, lane);
      if (wave < 2)      MFMA_CHUNK(16, buf1, accR0, accR1);
      else if (wave == 2) MFMA_CHUNK(16, buf1, accS0, accS1);
      __syncthreads();
      if (wave < 2)      MFMA_CHUNK(32, buf0, accR0, accR1);
      else if (wave == 2) MFMA_CHUNK(32, buf0, accS0, accS1);
      __syncthreads();
    } else {
      wait2(myh0, 64 * p, (p >= 2) ? myh1 : nullptr, 64 * (p - 1));
      const unsigned short* h0s = h0ring + (size_t)((p - 1) & 3) * 65536;
      const unsigned short* h1s = h1ring + (size_t)((p - 2) & 3) * 65536;
      // chunks 0,1 = h0cur halves — issue both (16 glds16/wave in flight)
      stage_ring512(buf0, h0s,       mh, wave, lane);
      stage_ring512(buf1, h0s + 512, mh, wave, lane);
      __syncthreads();
      if (wave < 3) MFMA_CHUNK(0, buf0, accR0, accR1);
      __syncthreads();
      // chunk2 = h1prev[0..511]
      if (p == 1) stage_reg512(buf0, ench, ebase, 1024, f32, tid);
      else        stage_ring512(buf0, h1s, mh, wave, lane);
      if (wave < 3) MFMA_CHUNK(16, buf1, accR0, accR1);
      __syncthreads();
      // chunk3 = h1prev[512..1023]
      if (p == 1) stage_reg512(buf1, ench, ebase + 512, 1024, f32, tid);
      else        stage_ring512(buf1, h1s + 512, mh, wave, lane);
      if (wave < 2)      MFMA_CHUNK(32, buf0, accR0, accR1);
      else if (wave == 2) MFMA_CHUNK(32, buf0, accS0, accS1);
      __syncthreads();
      if (wave < 2)      MFMA_CHUNK(48, buf1, accR0, accR1);
      else if (wave == 2) MFMA_CHUNK(48, buf1, accS0, accS1);
      __syncthreads();
    }

    // ---- cross-wave gate exchange (FB aliases buf0; all MFMAs done) ----
    if (wave < 3) {
      #pragma unroll
      for (int i = 0; i < 4; ++i) {
        int row0 = lq * 4 + i;                      // C/D: row=quad*4+reg, col=ln
        FB[wave * 512 +  row0       * 16 + ln] = accR0[i];
        FB[wave * 512 + (16 + row0) * 16 + ln] = accR1[i];
        if (wave == 2) {
          FB[3 * 512 +  row0       * 16 + ln] = accS0[i];
          FB[3 * 512 + (16 + row0) * 16 + ln] = accS1[i];
        }
      }
    }
    __syncthreads();

    // ---- fused GRU pointwise + publish (2 cells/thread) ----
    #pragma unroll
    for (int half = 0; half < 2; ++half) {
      int rr = rb + 16 * half;
      int b  = mh * 32 + rr;
      float sr  = FB[0 * 512 + rr * 16 + c_];
      float sz  = FB[1 * 512 + rr * 16 + c_];
      float sni = FB[2 * 512 + rr * 16 + c_];
      float snh = FB[3 * 512 + rr * 16 + c_];
      float rg = 1.f / (1.f + __expf(-(sr + bir + bhr)));
      float zg = 1.f / (1.f + __expf(-(sz + biz + bhz)));
      float ng = tanhf(sni + bin_ + rg * (snh + bhn));   // r*(hn + bhh_n) !
      int swzj = jcol ^ ((b & 7) << 3);                  // pre-swizzled ring col
      float hp;
      if (l0) hp = (p == 0) ? lds1(ench, (size_t)b * 1024 + jcol, f32)
                            : b2f(h0ring[(size_t)((p - 1) & 3) * 65536
                                         + (size_t)b * 1024 + swzj]);
      else    hp = (p >= 2) ? b2f(h1ring[(size_t)((p - 2) & 3) * 65536
                                         + (size_t)b * 1024 + swzj])
                            : lds1(ench, (size_t)b * 1024 + jcol, f32);
      float hnew = (1.f - zg) * ng + zg * hp;
      unsigned short hb = f2b(hnew);
      if (l0) {
        h0ring[(size_t)(p & 3) * 65536 + (size_t)b * 1024 + swzj] = hb;
      } else {
        size_t oidx = ((size_t)b * 512 + (size_t)(p - 1)) * 1024 + jcol;
        if (f32) ((float*)out)[oidx] = hnew;
        else     ((unsigned short*)out)[oidx] = hb;
        h1ring[(size_t)((p - 1) & 3) * 65536 + (size_t)b * 1024 + swzj] = hb;
        if (p == 512) {
          size_t cidx = 33554432u + (size_t)b * 1024 + jcol;   // final carry h1
          if (f32) ((float*)out)[cidx] = hnew;
          else     ((unsigned short*)out)[cidx] = hb;
        }
      }
    }

    __threadfence();
    __syncthreads();
    if (tid == 0)
      __hip_atomic_fetch_add(l0 ? myh0 : myh1, 1,
                             __ATOMIC_RELEASE, __HIP_MEMORY_SCOPE_AGENT);
  }
}

extern "C" void kernel_launch(void* const* d_in, const int* in_sizes, int n_in,
                              void* d_out, int out_size, void* d_ws, size_t ws_size,
                              hipStream_t stream) {
  char* ws = (char*)d_ws;
  int* h0cnt = (int*)ws;                               // per-mh, strided 64B
  int* h1cnt = (int*)(ws + 128);                       // per-mh, strided 64B
  int* flag  = (int*)(ws + 256);
  unsigned short* h0ring = (unsigned short*)(ws + 4096);     // 512 KB
  unsigned short* h1ring = (unsigned short*)(ws + 528384);   // 512 KB

  // staged bf16 weights (only if ws fits): 22 MB starting at 1,052,672
  const size_t W0 = 1052672;
  unsigned short *w0s = nullptr, *w1s = nullptr, *w2s = nullptr, *w3s = nullptr;
  bool fits = ws_size >= (W0 + 22020096);
  if (fits) {
    w0s = (unsigned short*)(ws + W0);                 // Wih0b: 3,145,728 B
    w1s = (unsigned short*)(ws + W0 + 3145728);       // Whh0b: 6,291,456 B
    w2s = (unsigned short*)(ws + W0 + 9437184);       // Wih1b: 6,291,456 B
    w3s = (unsigned short*)(ws + W0 + 15728640);      // Whh1b: 6,291,456 B
  }

  hipMemsetAsync(d_ws, 0, 512, stream);               // counters + flag

  hipLaunchKernelGGL(detect_mode, dim3(1), dim3(256), 0, stream,
                     (const unsigned int*)d_in[3], flag);
  if (fits) {
    hipLaunchKernelGGL(cvt_w, dim3(256), dim3(256), 0, stream,
                       (const float*)d_in[3], w0s, 1572864, flag);
    hipLaunchKernelGGL(cvt_w, dim3(256), dim3(256), 0, stream,
                       (const float*)d_in[4], w1s, 3145728, flag);
    hipLaunchKernelGGL(cvt_w, dim3(256), dim3(256), 0, stream,
                       (const float*)d_in[7], w2s, 3145728, flag);
    hipLaunchKernelGGL(cvt_w, dim3(256), dim3(256), 0, stream,
                       (const float*)d_in[8], w3s, 3145728, flag);
  }

  hipLaunchKernelGGL(gru_persist, dim3(256), dim3(256), 0, stream,
                     d_in[0], d_in[2],
                     d_in[3], d_in[4], d_in[5], d_in[6],
                     d_in[7], d_in[8], d_in[9], d_in[10],
                     d_out, w0s, w1s, w2s, w3s,
                     h0cnt, h1cnt, flag, h0ring, h1ring);
}

// Round 3
// 8516.766 us; speedup vs baseline: 6.0116x; 3.4040x over previous
//
#include <hip/hip_runtime.h>
#include <hip/hip_bf16.h>

// GRU decoder, B=64, T=512, IN=512, H=1024, 2 layers.
// Persistent kernel, 256 WGs x 256 threads. Sync redesign: per-WG done-slot
// release-stores + relaxed ballot-polling (no RMW contention, no per-poll
// buffer_inv, no per-thread threadfence). Weights register-resident. 64KB
// static LDS, both ring halves staged concurrently via global_load_lds from
// pre-swizzled bf16 rings; x pre-swizzled to bf16 by cvt_x when ws fits.

typedef __attribute__((ext_vector_type(8))) short short8;
typedef __attribute__((ext_vector_type(4))) float floatx4;

__device__ __forceinline__ float b2f(unsigned short u) {
  union { unsigned int i; float f; } v; v.i = ((unsigned int)u) << 16; return v.f;
}
__device__ __forceinline__ unsigned short f2b(float f) {
  unsigned int xi = __float_as_uint(f);
  return (unsigned short)((xi + 0x7fffu + ((xi >> 16) & 1u)) >> 16);  // RNE
}
__device__ __forceinline__ short8 cvt8(const float* __restrict__ p) {
  float4 a = *(const float4*)p;
  float4 b = *(const float4*)(p + 4);
  short8 v;
  v[0] = (short)f2b(a.x); v[1] = (short)f2b(a.y);
  v[2] = (short)f2b(a.z); v[3] = (short)f2b(a.w);
  v[4] = (short)f2b(b.x); v[5] = (short)f2b(b.y);
  v[6] = (short)f2b(b.z); v[7] = (short)f2b(b.w);
  return v;
}
__device__ __forceinline__ short8 ld8(const void* base, size_t e, bool f32) {
  return f32 ? cvt8((const float*)base + e)
             : *(const short8*)((const unsigned short*)base + e);
}
__device__ __forceinline__ float lds1(const void* base, size_t e, bool f32) {
  return f32 ? ((const float*)base)[e] : b2f(((const unsigned short*)base)[e]);
}
// async global->LDS, 16B/lane; LDS dest = wave-uniform base + lane*16 (linear)
typedef const __attribute__((address_space(1))) void* gas1_t;
typedef __attribute__((address_space(3))) void* las3_t;
__device__ __forceinline__ void glds16(const void* g, void* l) {
  __builtin_amdgcn_global_load_lds((gas1_t)g, (las3_t)l, 16, 0, 0);
}

// Mode detect: weights ~U(-0.031,0.031). If data is bf16, every u32's LOW
// half-word is a weight (|v|<=0.031). If fp32, low 16 bits are random mantissa.
__global__ void detect_mode(const unsigned int* __restrict__ w, int* __restrict__ flag) {
  int bad = 0;
  #pragma unroll
  for (int j = 0; j < 4; ++j) {
    unsigned int u = w[threadIdx.x * 4 + j];
    float f = b2f((unsigned short)(u & 0xFFFFu));
    if (!(fabsf(f) <= 1.0f)) bad = 1;
  }
  if (bad) atomicOr(flag, 1);
}

__global__ __launch_bounds__(256)
void cvt_w(const float* __restrict__ src, unsigned short* __restrict__ dst, int n,
           const int* __restrict__ flag) {
  if (*flag == 0) return;                 // bf16 mode: no staging
  int stride = gridDim.x * 256 * 4;
  for (int i = (blockIdx.x * 256 + threadIdx.x) * 4; i + 3 < n; i += stride) {
    float4 f = *(const float4*)(src + i);
    ushort4 u;
    u.x = f2b(f.x); u.y = f2b(f.y); u.z = f2b(f.z); u.w = f2b(f.w);
    *(ushort4*)(dst + i) = u;
  }
}

// x [64,512,512] fp32 -> bf16, PRE-SWIZZLED: xs[b][t][k ^ ((b&7)<<3)] = x[b][t][k]
// (XOR permutes whole 8-elem blocks; short8 stores stay contiguous).
__global__ __launch_bounds__(256)
void cvt_x(const float* __restrict__ src, unsigned short* __restrict__ dst,
           const int* __restrict__ flag) {
  if (*flag == 0) return;
  int i = (blockIdx.x * 256 + threadIdx.x) * 8;      // 16,777,216 elems total
  int k = i & 511;
  int b = i >> 18;                                   // 512*512 = 2^18
  int dk = k ^ ((b & 7) << 3);
  float4 f0 = *(const float4*)(src + i);
  float4 f1 = *(const float4*)(src + i + 4);
  short8 v;
  v[0] = (short)f2b(f0.x); v[1] = (short)f2b(f0.y);
  v[2] = (short)f2b(f0.z); v[3] = (short)f2b(f0.w);
  v[4] = (short)f2b(f1.x); v[5] = (short)f2b(f1.y);
  v[6] = (short)f2b(f1.z); v[7] = (short)f2b(f1.w);
  *(short8*)(dst + (i - k) + dk) = v;
}

// Poll 64 done-slots with RELAXED loads (no buffer_inv per poll); one ACQUIRE
// after satisfied. a1 optional second array (backpressure).
__device__ __forceinline__ void wait_arr2(const int* a0, int t0,
                                          const int* a1, int t1) {
  if (threadIdx.x < 64) {
    for (;;) {
      int v0 = __hip_atomic_load(a0 + threadIdx.x, __ATOMIC_RELAXED,
                                 __HIP_MEMORY_SCOPE_AGENT);
      int v1 = t1;
      if (a1) v1 = __hip_atomic_load(a1 + threadIdx.x, __ATOMIC_RELAXED,
                                     __HIP_MEMORY_SCOPE_AGENT);
      if (__ballot((v0 < t0) || (v1 < t1)) == 0) break;
      __builtin_amdgcn_s_sleep(1);
    }
  }
  if (threadIdx.x == 0)
    (void)__hip_atomic_load(a0, __ATOMIC_ACQUIRE, __HIP_MEMORY_SCOPE_AGENT);
  __syncthreads();
}

// stage 32 rows x 512 elems via registers (fp32-cvt or bf16 copy), swizzled.
__device__ __forceinline__ void stage_reg512(char* __restrict__ buf, const void* __restrict__ src,
                                             size_t base, size_t stride, bool f32, int tid) {
  #pragma unroll
  for (int i = 0; i < 8; ++i) {
    int g = tid + i * 256;            // 0..2047
    int r = g >> 6, col8 = g & 63;
    short8 v = ld8(src, base + (size_t)r * stride + (size_t)(col8 * 8), f32);
    *(short8*)(buf + r * 1024 + ((col8 * 16) ^ ((r & 7) << 4))) = v;
  }
}

// stage 32 rows x 512 elems via global_load_lds from PRE-SWIZZLED ring half.
__device__ __forceinline__ void stage_ring512(char* __restrict__ buf,
                                              const unsigned short* __restrict__ src,
                                              int mh, int wave, int lane) {
  #pragma unroll
  for (int rr = 0; rr < 8; ++rr) {
    int r = wave * 8 + rr;
    glds16(src + (size_t)(mh * 32 + r) * 1024 + lane * 8, buf + r * 1024);
  }
}

// 16 MFMA steps over one 512-elem chunk; A rows ln / 16+ln, swizzled reads.
#define MFMA_CHUNK(CBASE, BUF, ACC0, ACC1)                                        \
  do { _Pragma("unroll")                                                          \
    for (int s = 0; s < 16; ++s) {                                                \
      int off = (s * 64 + lq * 16) ^ swz;                                         \
      short8 a0 = *(const short8*)((BUF) + ln * 1024 + off);                      \
      short8 a1 = *(const short8*)((BUF) + (16 + ln) * 1024 + off);               \
      ACC0 = __builtin_amdgcn_mfma_f32_16x16x32_bf16(a0, wreg[(CBASE) + s], ACC0, 0, 0, 0); \
      ACC1 = __builtin_amdgcn_mfma_f32_16x16x32_bf16(a1, wreg[(CBASE) + s], ACC1, 0, 0, 0); \
    } } while (0)

__global__ __launch_bounds__(256, 1)
void gru_persist(const void* __restrict__ x,     // [64,512,512]
                 const void* __restrict__ ench,  // [64,1024]
                 const void* __restrict__ Wih0, const void* __restrict__ Whh0,
                 const void* __restrict__ bih0, const void* __restrict__ bhh0,
                 const void* __restrict__ Wih1, const void* __restrict__ Whh1,
                 const void* __restrict__ bih1, const void* __restrict__ bhh1,
                 void* __restrict__ out,         // [64,512,1024] + [64,1024]
                 const unsigned short* __restrict__ wih0s,  // staged bf16 or null
                 const unsigned short* __restrict__ whh0s,
                 const unsigned short* __restrict__ wih1s,
                 const unsigned short* __restrict__ whh1s,
                 const unsigned short* __restrict__ xs,     // pre-swizzled bf16 x or null
                 int* __restrict__ h0done,       // [2][64] per-WG done slots
                 int* __restrict__ h1done,       // [2][64]
                 const int* __restrict__ flag,
                 unsigned short* __restrict__ h0ring,   // 4 x 64x1024 bf16, swizzled
                 unsigned short* __restrict__ h1ring)   // 4 x 64x1024 bf16, swizzled
{
  // 64 KB static: buf0 @0, buf1 @32768 (32 rows x 1024B each). FB (8KB gate
  // exchange) aliases buf0 bytes 0..8191 — written only after all MFMAs AND
  // all hp LDS reads of the step are complete.
  __shared__ __align__(16) char smem[65536];
  char* buf0 = smem;
  char* buf1 = smem + 32768;
  float* FB  = (float*)smem;

  const bool f32 = (__hip_atomic_load((int*)flag, __ATOMIC_RELAXED,
                                      __HIP_MEMORY_SCOPE_AGENT) != 0);
  const bool staged = f32 && (wih0s != nullptr);
  const unsigned short* xsw = (f32 && xs) ? xs : nullptr;

  const int tid  = threadIdx.x;
  const int wave = tid >> 6;
  const int lane = tid & 63;
  const int ln   = lane & 15;             // A-row / B-col within 16-tile
  const int lq   = lane >> 4;             // k-quad

  const int wg  = blockIdx.x;
  const bool l0 = (wg < 128);
  const int lw  = l0 ? wg : (wg - 128);
  const int mh  = lw & 1;                 // batch rows 32*mh..+31
  const int jt  = lw >> 1;                // output cols 16*jt..+15

  int* h0d = h0done + mh * 64;            // this mh's cohort slots
  int* h1d = h1done + mh * 64;

  // weight sources
  const void* WI; const void* WH; bool wf32;
  if (staged) { WI = l0 ? (const void*)wih0s : (const void*)wih1s;
                WH = l0 ? (const void*)whh0s : (const void*)whh1s; wf32 = false; }
  else        { WI = l0 ? Wih0 : Wih1; WH = l0 ? Whh0 : Whh1; wf32 = f32; }
  const int KWI = l0 ? 512 : 1024;
  size_t wi_off = 0, wh_off = 0;
  if (wave < 3) {
    int row = wave * 1024 + jt * 16 + ln;   // gate = wave
    wi_off = (size_t)row * KWI;
    wh_off = (size_t)row * 1024;
  }

  // ---- preload ALL weights into registers (fence/L2-inval immune) ----
  short8 wreg[64];
  if (wave < 3) {
    if (l0) {
      #pragma unroll
      for (int c = 0; c < 48; ++c) {
        int k = c * 32 + lq * 8;
        wreg[c] = (c < 16) ? ld8(WI, wi_off + k, wf32)
                           : ld8(WH, wh_off + (k - 512), wf32);
      }
    } else {
      #pragma unroll
      for (int c = 0; c < 64; ++c) {
        int k = c * 32 + lq * 8;
        wreg[c] = (c < 32) ? ld8(WI, wi_off + k, wf32)
                           : ld8(WH, wh_off + (k - 1024), wf32);
      }
    }
  }

  // ---- hoist biases ----
  const int c_   = tid & 15;
  const int rb   = tid >> 4;              // 0..15
  const int jcol = jt * 16 + c_;
  const void* bi = l0 ? bih0 : bih1;
  const void* bh = l0 ? bhh0 : bhh1;
  const float bir  = lds1(bi, jcol, f32),        bhr = lds1(bh, jcol, f32);
  const float biz  = lds1(bi, 1024 + jcol, f32), bhz = lds1(bh, 1024 + jcol, f32);
  const float bin_ = lds1(bi, 2048 + jcol, f32), bhn = lds1(bh, 2048 + jcol, f32);

  const int swz = (ln & 7) << 4;          // byte swizzle for MFMA ds_reads
  const size_t ebase = (size_t)mh * 32 * 1024;   // ench row base (elems)
  const int jj   = jcol & 511;
  const int hpm  = (rb & 7) << 4;         // hp LDS swizzle mask (rb+16 same)

  for (int p = 0; p <= 512; ++p) {
    if (l0 && p >= 512) break;
    if (!l0 && p == 0) continue;

    floatx4 accR0 = {0,0,0,0}, accR1 = {0,0,0,0};  // wave0:r wave1:z wave2:n_i
    floatx4 accS0 = {0,0,0,0}, accS1 = {0,0,0,0};  // wave2:n_h
    float hp0, hp1;

    if (l0) {
      // ---- x chunk (k 0..511): stage + MFMA BEFORE the wait ----
      if (xsw) {
        #pragma unroll
        for (int rr = 0; rr < 8; ++rr) {
          int r = wave * 8 + rr;
          glds16(xsw + ((size_t)(mh * 32 + r) * 512 + (size_t)p) * 512 + lane * 8,
                 buf0 + r * 1024);
        }
      } else {
        stage_reg512(buf0, x, (size_t)mh * 32 * 262144 + (size_t)p * 512, 262144, f32, tid);
      }
      __syncthreads();
      if (wave < 3) MFMA_CHUNK(0, buf0, accR0, accR1);
      // wait h0[p-1] + ring WAR backpressure (internal syncthreads guards restage)
      if (p >= 1) wait_arr2(h0d, p, (p >= 4) ? h1d : nullptr, p - 3);
      else        __syncthreads();
      const unsigned short* h0s = h0ring + (size_t)((p - 1) & 3) * 65536;
      if (p == 0) { stage_reg512(buf1, ench, ebase,       1024, f32, tid);
                    stage_reg512(buf0, ench, ebase + 512, 1024, f32, tid); }
      else        { stage_ring512(buf1, h0s,       mh, wave, lane);
                    stage_ring512(buf0, h0s + 512, mh, wave, lane); }
      __syncthreads();
      // hp from staged tile (identical bf16 bits to ring); exact fp32 at p==0
      if (p == 0) {
        hp0 = lds1(ench, (size_t)(mh * 32 + rb) * 1024 + jcol, f32);
        hp1 = lds1(ench, (size_t)(mh * 32 + rb + 16) * 1024 + jcol, f32);
      } else {
        const char* hb_ = (jcol < 512) ? buf1 : buf0;
        hp0 = b2f(*(const unsigned short*)(hb_ +  rb       * 1024 + ((2 * jj) ^ hpm)));
        hp1 = b2f(*(const unsigned short*)(hb_ + (rb + 16) * 1024 + ((2 * jj) ^ hpm)));
      }
      if (wave < 2)       { MFMA_CHUNK(16, buf1, accR0, accR1);
                            MFMA_CHUNK(32, buf0, accR0, accR1); }
      else if (wave == 2) { MFMA_CHUNK(16, buf1, accS0, accS1);
                            MFMA_CHUNK(32, buf0, accS0, accS1); }
      __syncthreads();
    } else {
      // ---- h1prev half first (own-cohort data, available early) ----
      wait_arr2(h1d, p - 1, nullptr, 0);
      const unsigned short* h1s = h1ring + (size_t)((p - 2) & 3) * 65536;
      if (p == 1) { stage_reg512(buf0, ench, ebase,       1024, f32, tid);
                    stage_reg512(buf1, ench, ebase + 512, 1024, f32, tid); }
      else        { stage_ring512(buf0, h1s,       mh, wave, lane);
                    stage_ring512(buf1, h1s + 512, mh, wave, lane); }
      __syncthreads();
      if (p == 1) {
        hp0 = lds1(ench, (size_t)(mh * 32 + rb) * 1024 + jcol, f32);
        hp1 = lds1(ench, (size_t)(mh * 32 + rb + 16) * 1024 + jcol, f32);
      } else {
        const char* hb_ = (jcol < 512) ? buf0 : buf1;
        hp0 = b2f(*(const unsigned short*)(hb_ +  rb       * 1024 + ((2 * jj) ^ hpm)));
        hp1 = b2f(*(const unsigned short*)(hb_ + (rb + 16) * 1024 + ((2 * jj) ^ hpm)));
      }
      if (wave < 2)       { MFMA_CHUNK(32, buf0, accR0, accR1);
                            MFMA_CHUNK(48, buf1, accR0, accR1); }
      else if (wave == 2) { MFMA_CHUNK(32, buf0, accS0, accS1);
                            MFMA_CHUNK(48, buf1, accS0, accS1); }
      // ---- h0cur half (fresh dependency) ----
      wait_arr2(h0d, p, nullptr, 0);       // internal syncthreads guards restage
      const unsigned short* h0s = h0ring + (size_t)((p - 1) & 3) * 65536;
      stage_ring512(buf0, h0s,       mh, wave, lane);
      stage_ring512(buf1, h0s + 512, mh, wave, lane);
      __syncthreads();
      if (wave < 3) { MFMA_CHUNK(0,  buf0, accR0, accR1);
                      MFMA_CHUNK(16, buf1, accR0, accR1); }
      __syncthreads();
    }

    // ---- cross-wave gate exchange (FB aliases buf0; all MFMAs + hp reads done) ----
    if (wave < 3) {
      #pragma unroll
      for (int i = 0; i < 4; ++i) {
        int row0 = lq * 4 + i;                      // C/D: row=quad*4+reg, col=ln
        FB[wave * 512 +  row0       * 16 + ln] = accR0[i];
        FB[wave * 512 + (16 + row0) * 16 + ln] = accR1[i];
        if (wave == 2) {
          FB[3 * 512 +  row0       * 16 + ln] = accS0[i];
          FB[3 * 512 + (16 + row0) * 16 + ln] = accS1[i];
        }
      }
    }
    __syncthreads();

    // ---- fused GRU pointwise + publish (2 cells/thread) ----
    #pragma unroll
    for (int half = 0; half < 2; ++half) {
      int rr = rb + 16 * half;
      int b  = mh * 32 + rr;
      float sr  = FB[0 * 512 + rr * 16 + c_];
      float sz  = FB[1 * 512 + rr * 16 + c_];
      float sni = FB[2 * 512 + rr * 16 + c_];
      float snh = FB[3 * 512 + rr * 16 + c_];
      float rg = 1.f / (1.f + __expf(-(sr + bir + bhr)));
      float zg = 1.f / (1.f + __expf(-(sz + biz + bhz)));
      float ng = tanhf(sni + bin_ + rg * (snh + bhn));   // r*(hn + bhh_n) !
      float hp = half ? hp1 : hp0;
      float hnew = (1.f - zg) * ng + zg * hp;
      unsigned short hb = f2b(hnew);
      int swzj = jcol ^ ((b & 7) << 3);                  // pre-swizzled ring col
      if (l0) {
        h0ring[(size_t)(p & 3) * 65536 + (size_t)b * 1024 + swzj] = hb;
      } else {
        size_t oidx = ((size_t)b * 512 + (size_t)(p - 1)) * 1024 + jcol;
        if (f32) ((float*)out)[oidx] = hnew;
        else     ((unsigned short*)out)[oidx] = hb;
        h1ring[(size_t)((p - 1) & 3) * 65536 + (size_t)b * 1024 + swzj] = hb;
        if (p == 512) {
          size_t cidx = 33554432u + (size_t)b * 1024 + jcol;   // final carry h1
          if (f32) ((float*)out)[cidx] = hnew;
          else     ((unsigned short*)out)[cidx] = hb;
        }
      }
    }

    // ---- publish: single release store to this WG's done slot ----
    __syncthreads();   // all WG stores issued (vmcnt drained pre-barrier)
    if (tid == 0) {
      if (l0) __hip_atomic_store(&h0d[jt], p + 1, __ATOMIC_RELEASE,
                                 __HIP_MEMORY_SCOPE_AGENT);
      else    __hip_atomic_store(&h1d[jt], p, __ATOMIC_RELEASE,
                                 __HIP_MEMORY_SCOPE_AGENT);
    }
  }
}

extern "C" void kernel_launch(void* const* d_in, const int* in_sizes, int n_in,
                              void* d_out, int out_size, void* d_ws, size_t ws_size,
                              hipStream_t stream) {
  char* ws = (char*)d_ws;
  int* h0done = (int*)ws;                              // [2][64] = 512 B
  int* h1done = (int*)(ws + 512);                      // [2][64] = 512 B
  int* flag   = (int*)(ws + 1024);
  unsigned short* h0ring = (unsigned short*)(ws + 4096);     // 512 KB
  unsigned short* h1ring = (unsigned short*)(ws + 528384);   // 512 KB

  // staged bf16 weights (only if ws fits): 22 MB starting at 1,052,672
  const size_t W0 = 1052672;
  unsigned short *w0s = nullptr, *w1s = nullptr, *w2s = nullptr, *w3s = nullptr;
  bool fits = ws_size >= (W0 + 22020096);
  if (fits) {
    w0s = (unsigned short*)(ws + W0);                 // Wih0b: 3,145,728 B
    w1s = (unsigned short*)(ws + W0 + 3145728);       // Whh0b: 6,291,456 B
    w2s = (unsigned short*)(ws + W0 + 9437184);       // Wih1b: 6,291,456 B
    w3s = (unsigned short*)(ws + W0 + 15728640);      // Whh1b: 6,291,456 B
  }
  // pre-swizzled bf16 x (33.5 MB) if ws also fits that
  const size_t XS0 = W0 + 22020096;                   // 23,072,768
  unsigned short* xsw = nullptr;
  bool fits_x = fits && (ws_size >= XS0 + 33554432);
  if (fits_x) xsw = (unsigned short*)(ws + XS0);

  hipMemsetAsync(d_ws, 0, 2048, stream);              // done slots + flag

  hipLaunchKernelGGL(detect_mode, dim3(1), dim3(256), 0, stream,
                     (const unsigned int*)d_in[3], flag);
  if (fits) {
    hipLaunchKernelGGL(cvt_w, dim3(256), dim3(256), 0, stream,
                       (const float*)d_in[3], w0s, 1572864, flag);
    hipLaunchKernelGGL(cvt_w, dim3(256), dim3(256), 0, stream,
                       (const float*)d_in[4], w1s, 3145728, flag);
    hipLaunchKernelGGL(cvt_w, dim3(256), dim3(256), 0, stream,
                       (const float*)d_in[7], w2s, 3145728, flag);
    hipLaunchKernelGGL(cvt_w, dim3(256), dim3(256), 0, stream,
                       (const float*)d_in[8], w3s, 3145728, flag);
  }
  if (fits_x) {
    hipLaunchKernelGGL(cvt_x, dim3(8192), dim3(256), 0, stream,
                       (const float*)d_in[0], xsw, flag);
  }

  hipLaunchKernelGGL(gru_persist, dim3(256), dim3(256), 0, stream,
                     d_in[0], d_in[2],
                     d_in[3], d_in[4], d_in[5], d_in[6],
                     d_in[7], d_in[8], d_in[9], d_in[10],
                     d_out, w0s, w1s, w2s, w3s, xsw,
                     h0done, h1done, flag, h0ring, h1ring);
}

// Round 4
// 4961.176 us; speedup vs baseline: 10.3200x; 1.7167x over previous
//
#include <hip/hip_runtime.h>
#include <hip/hip_bf16.h>

// GRU decoder, B=64, T=512, IN=512, H=1024, 2 layers.
// Persistent kernel, 256 WGs x 256 threads. FENCE-FREE sync: all cross-WG data
// (rings, done slots) via relaxed agent-scope atomics (sc1 read/write-through);
// zero buffer_inv / buffer_wbl2 in the loop. Weights register-resident. 64KB
// static LDS; ring staging via atomic u64 loads + ds_write; x via
// global_load_lds from pre-swizzled bf16 copy (private, cached).

typedef __attribute__((ext_vector_type(8))) short short8;
typedef __attribute__((ext_vector_type(4))) float floatx4;

__device__ __forceinline__ float b2f(unsigned short u) {
  union { unsigned int i; float f; } v; v.i = ((unsigned int)u) << 16; return v.f;
}
__device__ __forceinline__ unsigned short f2b(float f) {
  unsigned int xi = __float_as_uint(f);
  return (unsigned short)((xi + 0x7fffu + ((xi >> 16) & 1u)) >> 16);  // RNE
}
__device__ __forceinline__ short8 cvt8(const float* __restrict__ p) {
  float4 a = *(const float4*)p;
  float4 b = *(const float4*)(p + 4);
  short8 v;
  v[0] = (short)f2b(a.x); v[1] = (short)f2b(a.y);
  v[2] = (short)f2b(a.z); v[3] = (short)f2b(a.w);
  v[4] = (short)f2b(b.x); v[5] = (short)f2b(b.y);
  v[6] = (short)f2b(b.z); v[7] = (short)f2b(b.w);
  return v;
}
__device__ __forceinline__ short8 ld8(const void* base, size_t e, bool f32) {
  return f32 ? cvt8((const float*)base + e)
             : *(const short8*)((const unsigned short*)base + e);
}
__device__ __forceinline__ float lds1(const void* base, size_t e, bool f32) {
  return f32 ? ((const float*)base)[e] : b2f(((const unsigned short*)base)[e]);
}
typedef const __attribute__((address_space(1))) void* gas1_t;
typedef __attribute__((address_space(3))) void* las3_t;
__device__ __forceinline__ void glds16(const void* g, void* l) {
  __builtin_amdgcn_global_load_lds((gas1_t)g, (las3_t)l, 16, 0, 0);
}

// Mode detect: weights ~U(-0.031,0.031). If data is bf16, every u32's LOW
// half-word is a weight (|v|<=0.031). If fp32, low 16 bits are random mantissa.
__global__ void detect_mode(const unsigned int* __restrict__ w, int* __restrict__ flag) {
  int bad = 0;
  #pragma unroll
  for (int j = 0; j < 4; ++j) {
    unsigned int u = w[threadIdx.x * 4 + j];
    float f = b2f((unsigned short)(u & 0xFFFFu));
    if (!(fabsf(f) <= 1.0f)) bad = 1;
  }
  if (bad) atomicOr(flag, 1);
}

__global__ __launch_bounds__(256)
void cvt_w(const float* __restrict__ src, unsigned short* __restrict__ dst, int n,
           const int* __restrict__ flag) {
  if (*flag == 0) return;                 // bf16 mode: no staging
  int stride = gridDim.x * 256 * 4;
  for (int i = (blockIdx.x * 256 + threadIdx.x) * 4; i + 3 < n; i += stride) {
    float4 f = *(const float4*)(src + i);
    ushort4 u;
    u.x = f2b(f.x); u.y = f2b(f.y); u.z = f2b(f.z); u.w = f2b(f.w);
    *(ushort4*)(dst + i) = u;
  }
}

// x [64,512,512] fp32 -> bf16, PRE-SWIZZLED: xs[b][t][k ^ ((b&7)<<3)] = x[b][t][k]
__global__ __launch_bounds__(256)
void cvt_x(const float* __restrict__ src, unsigned short* __restrict__ dst,
           const int* __restrict__ flag) {
  if (*flag == 0) return;
  int i = (blockIdx.x * 256 + threadIdx.x) * 8;      // 16,777,216 elems total
  int k = i & 511;
  int b = i >> 18;                                   // 512*512 = 2^18
  int dk = k ^ ((b & 7) << 3);
  float4 f0 = *(const float4*)(src + i);
  float4 f1 = *(const float4*)(src + i + 4);
  short8 v;
  v[0] = (short)f2b(f0.x); v[1] = (short)f2b(f0.y);
  v[2] = (short)f2b(f0.z); v[3] = (short)f2b(f0.w);
  v[4] = (short)f2b(f1.x); v[5] = (short)f2b(f1.y);
  v[6] = (short)f2b(f1.z); v[7] = (short)f2b(f1.w);
  *(short8*)(dst + (i - k) + dk) = v;
}

// Poll 64 done-slots (64B-strided) with RELAXED agent loads; no inv, no acquire.
// __syncthreads (full compiler+exec barrier) orders subsequent ring reads.
__device__ __forceinline__ void wait_arr2(const int* a0, int t0,
                                          const int* a1, int t1) {
  if (threadIdx.x < 64) {
    for (;;) {
      int v0 = __hip_atomic_load(a0 + threadIdx.x * 16, __ATOMIC_RELAXED,
                                 __HIP_MEMORY_SCOPE_AGENT);
      int v1 = t1;
      if (a1) v1 = __hip_atomic_load(a1 + threadIdx.x * 16, __ATOMIC_RELAXED,
                                     __HIP_MEMORY_SCOPE_AGENT);
      if (__ballot((v0 < t0) || (v1 < t1)) == 0) break;
      __builtin_amdgcn_s_sleep(1);
    }
  }
  __syncthreads();
}

// stage 32 rows x 512 elems via registers (fp32-cvt or bf16 copy), swizzled.
__device__ __forceinline__ void stage_reg512(char* __restrict__ buf, const void* __restrict__ src,
                                             size_t base, size_t stride, bool f32, int tid) {
  #pragma unroll
  for (int i = 0; i < 8; ++i) {
    int g = tid + i * 256;            // 0..2047
    int r = g >> 6, col8 = g & 63;
    short8 v = ld8(src, base + (size_t)r * stride + (size_t)(col8 * 8), f32);
    *(short8*)(buf + r * 1024 + ((col8 * 16) ^ ((r & 7) << 4))) = v;
  }
}

// Fence-free ring staging: 32 rows x 1024 elems (pre-swizzled) read with
// RELAXED agent atomic u64 loads (sc1 read-through; no acquire-inv needed),
// written to LDS. cols 0..511 -> bufLo, 512..1023 -> bufHi. Thread t covers
// u64-column t across all 32 rows (coalesced 2KB/row per iteration).
__device__ __forceinline__ void stage_rows_atomic(char* __restrict__ bufLo,
                                                  char* __restrict__ bufHi,
                                                  const unsigned short* __restrict__ rowbase,
                                                  int tid) {
  const int col = tid * 4;                  // elem col of this thread's u64
  char* d = (col < 512) ? (bufLo + col * 2) : (bufHi + (col - 512) * 2);
  #pragma unroll
  for (int i = 0; i < 32; i += 4) {
    unsigned long long t0[4];
    #pragma unroll
    for (int j = 0; j < 4; ++j)
      t0[j] = __hip_atomic_load(
          (const unsigned long long*)(rowbase + (size_t)(i + j) * 1024) + tid,
          __ATOMIC_RELAXED, __HIP_MEMORY_SCOPE_AGENT);
    #pragma unroll
    for (int j = 0; j < 4; ++j)
      *(unsigned long long*)(d + (i + j) * 1024) = t0[j];
  }
}

// 16 MFMA steps over one 512-elem chunk; A rows ln / 16+ln, swizzled reads.
#define MFMA_CHUNK(CBASE, BUF, ACC0, ACC1)                                        \
  do { _Pragma("unroll")                                                          \
    for (int s = 0; s < 16; ++s) {                                                \
      int off = (s * 64 + lq * 16) ^ swz;                                         \
      short8 a0 = *(const short8*)((BUF) + ln * 1024 + off);                      \
      short8 a1 = *(const short8*)((BUF) + (16 + ln) * 1024 + off);               \
      ACC0 = __builtin_amdgcn_mfma_f32_16x16x32_bf16(a0, wreg[(CBASE) + s], ACC0, 0, 0, 0); \
      ACC1 = __builtin_amdgcn_mfma_f32_16x16x32_bf16(a1, wreg[(CBASE) + s], ACC1, 0, 0, 0); \
    } } while (0)

__global__ __launch_bounds__(256, 1)
void gru_persist(const void* __restrict__ x,     // [64,512,512]
                 const void* __restrict__ ench,  // [64,1024]
                 const void* __restrict__ Wih0, const void* __restrict__ Whh0,
                 const void* __restrict__ bih0, const void* __restrict__ bhh0,
                 const void* __restrict__ Wih1, const void* __restrict__ Whh1,
                 const void* __restrict__ bih1, const void* __restrict__ bhh1,
                 void* __restrict__ out,         // [64,512,1024] + [64,1024]
                 const unsigned short* __restrict__ wih0s,  // staged bf16 or null
                 const unsigned short* __restrict__ whh0s,
                 const unsigned short* __restrict__ wih1s,
                 const unsigned short* __restrict__ whh1s,
                 const unsigned short* __restrict__ xs,     // pre-swizzled bf16 x or null
                 int* __restrict__ h0done,       // [2][64][16] ints (64B slots)
                 int* __restrict__ h1done,       // [2][64][16]
                 const int* __restrict__ flag,
                 unsigned short* __restrict__ h0ring,   // 4 x 64x1024 bf16, swizzled
                 unsigned short* __restrict__ h1ring)   // 4 x 64x1024 bf16, swizzled
{
  // 64 KB static: buf0 @0, buf1 @32768 (32 rows x 1024B each). FB (8KB gate
  // exchange) aliases buf0 bytes 0..8191 — written only after all MFMAs AND
  // all hp LDS reads of the step are complete.
  __shared__ __align__(16) char smem[65536];
  char* buf0 = smem;
  char* buf1 = smem + 32768;
  float* FB  = (float*)smem;

  const bool f32 = (__hip_atomic_load((int*)flag, __ATOMIC_RELAXED,
                                      __HIP_MEMORY_SCOPE_AGENT) != 0);
  const bool staged = f32 && (wih0s != nullptr);
  const unsigned short* xsw = (f32 && xs) ? xs : nullptr;

  const int tid  = threadIdx.x;
  const int wave = tid >> 6;
  const int lane = tid & 63;
  const int ln   = lane & 15;             // A-row / B-col within 16-tile
  const int lq   = lane >> 4;             // k-quad

  const int wg  = blockIdx.x;
  const bool l0 = (wg < 128);
  const int lw  = l0 ? wg : (wg - 128);
  const int mh  = lw & 1;                 // batch rows 32*mh..+31
  const int jt  = lw >> 1;                // output cols 16*jt..+15

  int* h0d = h0done + mh * 1024;          // this mh's cohort slots (64 x 16 ints)
  int* h1d = h1done + mh * 1024;

  // weight sources
  const void* WI; const void* WH; bool wf32;
  if (staged) { WI = l0 ? (const void*)wih0s : (const void*)wih1s;
                WH = l0 ? (const void*)whh0s : (const void*)whh1s; wf32 = false; }
  else        { WI = l0 ? Wih0 : Wih1; WH = l0 ? Whh0 : Whh1; wf32 = f32; }
  const int KWI = l0 ? 512 : 1024;
  size_t wi_off = 0, wh_off = 0;
  if (wave < 3) {
    int row = wave * 1024 + jt * 16 + ln;   // gate = wave
    wi_off = (size_t)row * KWI;
    wh_off = (size_t)row * 1024;
  }

  // ---- preload ALL weights into registers (L2-state immune) ----
  short8 wreg[64];
  if (wave < 3) {
    if (l0) {
      #pragma unroll
      for (int c = 0; c < 48; ++c) {
        int k = c * 32 + lq * 8;
        wreg[c] = (c < 16) ? ld8(WI, wi_off + k, wf32)
                           : ld8(WH, wh_off + (k - 512), wf32);
      }
    } else {
      #pragma unroll
      for (int c = 0; c < 64; ++c) {
        int k = c * 32 + lq * 8;
        wreg[c] = (c < 32) ? ld8(WI, wi_off + k, wf32)
                           : ld8(WH, wh_off + (k - 1024), wf32);
      }
    }
  }

  // ---- pointwise mapping: thread -> (row rr, col pair cp) ----
  const int cp   = tid & 7;
  const int rr   = tid >> 3;              // 0..31
  const int col0 = jt * 16 + cp * 2;      // even
  const void* bi = l0 ? bih0 : bih1;
  const void* bh = l0 ? bhh0 : bhh1;
  const float bir0 = lds1(bi, col0, f32),        bir1 = lds1(bi, col0 + 1, f32);
  const float bhr0 = lds1(bh, col0, f32),        bhr1 = lds1(bh, col0 + 1, f32);
  const float biz0 = lds1(bi, 1024 + col0, f32), biz1 = lds1(bi, 1025 + col0, f32);
  const float bhz0 = lds1(bh, 1024 + col0, f32), bhz1 = lds1(bh, 1025 + col0, f32);
  const float bin0 = lds1(bi, 2048 + col0, f32), bin1 = lds1(bi, 2049 + col0, f32);
  const float bhn0 = lds1(bh, 2048 + col0, f32), bhn1 = lds1(bh, 2049 + col0, f32);

  const int swz = (ln & 7) << 4;          // byte swizzle for MFMA ds_reads
  const size_t ebase = (size_t)mh * 32 * 1024;   // ench row base (elems)
  const int jj   = col0 & 511;
  const int hpsw = (2 * jj) ^ ((rr & 7) << 4);   // hp pair byte offset in LDS row
  const int brow = mh * 32 + rr;
  const int rsw  = col0 ^ ((brow & 7) << 3);     // pre-swizzled ring col (pair)

  for (int p = 0; p <= 512; ++p) {
    if (l0 && p >= 512) break;
    if (!l0 && p == 0) continue;

    floatx4 accR0 = {0,0,0,0}, accR1 = {0,0,0,0};  // wave0:r wave1:z wave2:n_i
    floatx4 accS0 = {0,0,0,0}, accS1 = {0,0,0,0};  // wave2:n_h
    float hp0, hp1;

    if (l0) {
      // ---- x chunk (k 0..511): private data, cached path ----
      if (xsw) {
        #pragma unroll
        for (int rr8 = 0; rr8 < 8; ++rr8) {
          int r = wave * 8 + rr8;
          glds16(xsw + ((size_t)(mh * 32 + r) * 512 + (size_t)p) * 512 + lane * 8,
                 buf0 + r * 1024);
        }
      } else {
        stage_reg512(buf0, x, (size_t)mh * 32 * 262144 + (size_t)p * 512, 262144, f32, tid);
      }
      __syncthreads();
      if (wave < 3) MFMA_CHUNK(0, buf0, accR0, accR1);
      if (p >= 1) wait_arr2(h0d, p, (p >= 4) ? h1d : nullptr, p - 3);
      else        __syncthreads();        // protect buf re-stage vs chunk0 reads
      if (p == 0) { stage_reg512(buf1, ench, ebase,       1024, f32, tid);
                    stage_reg512(buf0, ench, ebase + 512, 1024, f32, tid); }
      else        stage_rows_atomic(buf1, buf0,
                      h0ring + (size_t)((p - 1) & 3) * 65536 + (size_t)mh * 32768, tid);
      __syncthreads();
      if (p == 0) {
        hp0 = lds1(ench, (size_t)brow * 1024 + col0, f32);
        hp1 = lds1(ench, (size_t)brow * 1024 + col0 + 1, f32);
      } else {
        const char* hb_ = (col0 < 512) ? buf1 : buf0;
        unsigned int pv = *(const unsigned int*)(hb_ + rr * 1024 + hpsw);
        hp0 = b2f((unsigned short)(pv & 0xFFFFu));
        hp1 = b2f((unsigned short)(pv >> 16));
      }
      if (wave < 2)       { MFMA_CHUNK(16, buf1, accR0, accR1);
                            MFMA_CHUNK(32, buf0, accR0, accR1); }
      else if (wave == 2) { MFMA_CHUNK(16, buf1, accS0, accS1);
                            MFMA_CHUNK(32, buf0, accS0, accS1); }
      __syncthreads();
    } else {
      // ---- h1prev (own-cohort, available early) ----
      wait_arr2(h1d, p - 1, nullptr, 0);
      if (p == 1) { stage_reg512(buf0, ench, ebase,       1024, f32, tid);
                    stage_reg512(buf1, ench, ebase + 512, 1024, f32, tid); }
      else        stage_rows_atomic(buf0, buf1,
                      h1ring + (size_t)((p - 2) & 3) * 65536 + (size_t)mh * 32768, tid);
      __syncthreads();
      if (p == 1) {
        hp0 = lds1(ench, (size_t)brow * 1024 + col0, f32);
        hp1 = lds1(ench, (size_t)brow * 1024 + col0 + 1, f32);
      } else {
        const char* hb_ = (col0 < 512) ? buf0 : buf1;
        unsigned int pv = *(const unsigned int*)(hb_ + rr * 1024 + hpsw);
        hp0 = b2f((unsigned short)(pv & 0xFFFFu));
        hp1 = b2f((unsigned short)(pv >> 16));
      }
      if (wave < 2)       { MFMA_CHUNK(32, buf0, accR0, accR1);
                            MFMA_CHUNK(48, buf1, accR0, accR1); }
      else if (wave == 2) { MFMA_CHUNK(32, buf0, accS0, accS1);
                            MFMA_CHUNK(48, buf1, accS0, accS1); }
      // ---- h0cur (fresh dependency); wait contains the guarding barrier ----
      wait_arr2(h0d, p, nullptr, 0);
      stage_rows_atomic(buf0, buf1,
          h0ring + (size_t)((p - 1) & 3) * 65536 + (size_t)mh * 32768, tid);
      __syncthreads();
      if (wave < 3) { MFMA_CHUNK(0,  buf0, accR0, accR1);
                      MFMA_CHUNK(16, buf1, accR0, accR1); }
      __syncthreads();
    }

    // ---- cross-wave gate exchange (FB aliases buf0; all MFMAs + hp reads done) ----
    if (wave < 3) {
      #pragma unroll
      for (int i = 0; i < 4; ++i) {
        int row0 = lq * 4 + i;                      // C/D: row=quad*4+reg, col=ln
        FB[wave * 512 +  row0       * 16 + ln] = accR0[i];
        FB[wave * 512 + (16 + row0) * 16 + ln] = accR1[i];
        if (wave == 2) {
          FB[3 * 512 +  row0       * 16 + ln] = accS0[i];
          FB[3 * 512 + (16 + row0) * 16 + ln] = accS1[i];
        }
      }
    }
    __syncthreads();

    // ---- fused GRU pointwise + publish (1 col-pair/thread, 32 rows) ----
    {
      int fbb = rr * 16 + cp * 2;
      float sr0  = FB[fbb],        sr1  = FB[fbb + 1];
      float sz0  = FB[512 + fbb],  sz1  = FB[513 + fbb];
      float sni0 = FB[1024 + fbb], sni1 = FB[1025 + fbb];
      float snh0 = FB[1536 + fbb], snh1 = FB[1537 + fbb];
      float rg0 = 1.f / (1.f + __expf(-(sr0 + bir0 + bhr0)));
      float rg1 = 1.f / (1.f + __expf(-(sr1 + bir1 + bhr1)));
      float zg0 = 1.f / (1.f + __expf(-(sz0 + biz0 + bhz0)));
      float zg1 = 1.f / (1.f + __expf(-(sz1 + biz1 + bhz1)));
      float ng0 = tanhf(sni0 + bin0 + rg0 * (snh0 + bhn0));   // r*(hn + bhh_n) !
      float ng1 = tanhf(sni1 + bin1 + rg1 * (snh1 + bhn1));
      float hnew0 = (1.f - zg0) * ng0 + zg0 * hp0;
      float hnew1 = (1.f - zg1) * ng1 + zg1 * hp1;
      unsigned int pair = (unsigned int)f2b(hnew0) | ((unsigned int)f2b(hnew1) << 16);
      if (l0) {
        __hip_atomic_store((unsigned int*)(h0ring + (size_t)(p & 3) * 65536
                                           + (size_t)brow * 1024 + rsw),
                           pair, __ATOMIC_RELAXED, __HIP_MEMORY_SCOPE_AGENT);
      } else {
        size_t oidx = ((size_t)brow * 512 + (size_t)(p - 1)) * 1024 + col0;
        if (f32) { float2 o2 = {hnew0, hnew1}; *(float2*)((float*)out + oidx) = o2; }
        else     *(unsigned int*)((unsigned short*)out + oidx) = pair;
        __hip_atomic_store((unsigned int*)(h1ring + (size_t)((p - 1) & 3) * 65536
                                           + (size_t)brow * 1024 + rsw),
                           pair, __ATOMIC_RELAXED, __HIP_MEMORY_SCOPE_AGENT);
        if (p == 512) {
          size_t cidx = 33554432u + (size_t)brow * 1024 + col0;   // final carry h1
          if (f32) { ((float*)out)[cidx] = hnew0; ((float*)out)[cidx + 1] = hnew1; }
          else     *(unsigned int*)((unsigned short*)out + cidx) = pair;
        }
      }
    }

    // ---- publish: barrier drains vmcnt (sc1 stores at coherence point),
    //      then one relaxed flag store. No wbl2, no inv. ----
    __syncthreads();
    if (tid == 0) {
      if (l0) __hip_atomic_store(&h0d[jt * 16], p + 1, __ATOMIC_RELAXED,
                                 __HIP_MEMORY_SCOPE_AGENT);
      else    __hip_atomic_store(&h1d[jt * 16], p, __ATOMIC_RELAXED,
                                 __HIP_MEMORY_SCOPE_AGENT);
    }
  }
}

extern "C" void kernel_launch(void* const* d_in, const int* in_sizes, int n_in,
                              void* d_out, int out_size, void* d_ws, size_t ws_size,
                              hipStream_t stream) {
  char* ws = (char*)d_ws;
  int* h0done = (int*)ws;                              // [2][64][16] = 8192 B
  int* h1done = (int*)(ws + 8192);                     // [2][64][16] = 8192 B
  int* flag   = (int*)(ws + 16384);
  unsigned short* h0ring = (unsigned short*)(ws + 32768);    // 512 KB
  unsigned short* h1ring = (unsigned short*)(ws + 557056);   // 512 KB

  // staged bf16 weights (only if ws fits): 22 MB starting at 1,081,344
  const size_t W0 = 1081344;
  unsigned short *w0s = nullptr, *w1s = nullptr, *w2s = nullptr, *w3s = nullptr;
  bool fits = ws_size >= (W0 + 22020096);
  if (fits) {
    w0s = (unsigned short*)(ws + W0);                 // Wih0b: 3,145,728 B
    w1s = (unsigned short*)(ws + W0 + 3145728);       // Whh0b: 6,291,456 B
    w2s = (unsigned short*)(ws + W0 + 9437184);       // Wih1b: 6,291,456 B
    w3s = (unsigned short*)(ws + W0 + 15728640);      // Whh1b: 6,291,456 B
  }
  // pre-swizzled bf16 x (33.5 MB) if ws also fits that
  const size_t XS0 = W0 + 22020096;                   // 23,101,440
  unsigned short* xsw = nullptr;
  bool fits_x = fits && (ws_size >= XS0 + 33554432);
  if (fits_x) xsw = (unsigned short*)(ws + XS0);

  hipMemsetAsync(d_ws, 0, 20480, stream);             // done slots + flag

  hipLaunchKernelGGL(detect_mode, dim3(1), dim3(256), 0, stream,
                     (const unsigned int*)d_in[3], flag);
  if (fits) {
    hipLaunchKernelGGL(cvt_w, dim3(256), dim3(256), 0, stream,
                       (const float*)d_in[3], w0s, 1572864, flag);
    hipLaunchKernelGGL(cvt_w, dim3(256), dim3(256), 0, stream,
                       (const float*)d_in[4], w1s, 3145728, flag);
    hipLaunchKernelGGL(cvt_w, dim3(256), dim3(256), 0, stream,
                       (const float*)d_in[7], w2s, 3145728, flag);
    hipLaunchKernelGGL(cvt_w, dim3(256), dim3(256), 0, stream,
                       (const float*)d_in[8], w3s, 3145728, flag);
  }
  if (fits_x) {
    hipLaunchKernelGGL(cvt_x, dim3(8192), dim3(256), 0, stream,
                       (const float*)d_in[0], xsw, flag);
  }

  hipLaunchKernelGGL(gru_persist, dim3(256), dim3(256), 0, stream,
                     d_in[0], d_in[2],
                     d_in[3], d_in[4], d_in[5], d_in[6],
                     d_in[7], d_in[8], d_in[9], d_in[10],
                     d_out, w0s, w1s, w2s, w3s, xsw,
                     h0done, h1done, flag, h0ring, h1ring);
}

// Round 5
// 3812.598 us; speedup vs baseline: 13.4290x; 1.3013x over previous
//
#include <hip/hip_runtime.h>
#include <hip/hip_bf16.h>

// GRU decoder, B=64, T=512, IN=512, H=1024, 2 layers.
// Persistent kernel, 256 WGs x 256 threads. FENCE-FREE sync (relaxed agent
// atomics for flags + ring WRITES). NEW: full-depth (no-reuse) rings so ring
// READS use plain global_load_lds -> L2-shared among same-XCD consumers
// (sc1 atomic loads can never hit L2; they were saturating the L3 path at
// ~2.5 TB/s). Fallback to 4-deep + atomic reads per-ring if ws too small.
// Weights register-resident. 64KB static LDS.

typedef __attribute__((ext_vector_type(8))) short short8;
typedef __attribute__((ext_vector_type(4))) float floatx4;

__device__ __forceinline__ float b2f(unsigned short u) {
  union { unsigned int i; float f; } v; v.i = ((unsigned int)u) << 16; return v.f;
}
__device__ __forceinline__ unsigned short f2b(float f) {
  unsigned int xi = __float_as_uint(f);
  return (unsigned short)((xi + 0x7fffu + ((xi >> 16) & 1u)) >> 16);  // RNE
}
__device__ __forceinline__ short8 cvt8(const float* __restrict__ p) {
  float4 a = *(const float4*)p;
  float4 b = *(const float4*)(p + 4);
  short8 v;
  v[0] = (short)f2b(a.x); v[1] = (short)f2b(a.y);
  v[2] = (short)f2b(a.z); v[3] = (short)f2b(a.w);
  v[4] = (short)f2b(b.x); v[5] = (short)f2b(b.y);
  v[6] = (short)f2b(b.z); v[7] = (short)f2b(b.w);
  return v;
}
__device__ __forceinline__ short8 ld8(const void* base, size_t e, bool f32) {
  return f32 ? cvt8((const float*)base + e)
             : *(const short8*)((const unsigned short*)base + e);
}
__device__ __forceinline__ float lds1(const void* base, size_t e, bool f32) {
  return f32 ? ((const float*)base)[e] : b2f(((const unsigned short*)base)[e]);
}
typedef const __attribute__((address_space(1))) void* gas1_t;
typedef __attribute__((address_space(3))) void* las3_t;
__device__ __forceinline__ void glds16(const void* g, void* l) {
  __builtin_amdgcn_global_load_lds((gas1_t)g, (las3_t)l, 16, 0, 0);
}

// Mode detect: weights ~U(-0.031,0.031). If data is bf16, every u32's LOW
// half-word is a weight (|v|<=0.031). If fp32, low 16 bits are random mantissa.
__global__ void detect_mode(const unsigned int* __restrict__ w, int* __restrict__ flag) {
  int bad = 0;
  #pragma unroll
  for (int j = 0; j < 4; ++j) {
    unsigned int u = w[threadIdx.x * 4 + j];
    float f = b2f((unsigned short)(u & 0xFFFFu));
    if (!(fabsf(f) <= 1.0f)) bad = 1;
  }
  if (bad) atomicOr(flag, 1);
}

__global__ __launch_bounds__(256)
void cvt_w(const float* __restrict__ src, unsigned short* __restrict__ dst, int n,
           const int* __restrict__ flag) {
  if (*flag == 0) return;                 // bf16 mode: no staging
  int stride = gridDim.x * 256 * 4;
  for (int i = (blockIdx.x * 256 + threadIdx.x) * 4; i + 3 < n; i += stride) {
    float4 f = *(const float4*)(src + i);
    ushort4 u;
    u.x = f2b(f.x); u.y = f2b(f.y); u.z = f2b(f.z); u.w = f2b(f.w);
    *(ushort4*)(dst + i) = u;
  }
}

// x [64,512,512] fp32 -> bf16, PRE-SWIZZLED: xs[b][t][k ^ ((b&7)<<3)] = x[b][t][k]
__global__ __launch_bounds__(256)
void cvt_x(const float* __restrict__ src, unsigned short* __restrict__ dst,
           const int* __restrict__ flag) {
  if (*flag == 0) return;
  int i = (blockIdx.x * 256 + threadIdx.x) * 8;      // 16,777,216 elems total
  int k = i & 511;
  int b = i >> 18;                                   // 512*512 = 2^18
  int dk = k ^ ((b & 7) << 3);
  float4 f0 = *(const float4*)(src + i);
  float4 f1 = *(const float4*)(src + i + 4);
  short8 v;
  v[0] = (short)f2b(f0.x); v[1] = (short)f2b(f0.y);
  v[2] = (short)f2b(f0.z); v[3] = (short)f2b(f0.w);
  v[4] = (short)f2b(f1.x); v[5] = (short)f2b(f1.y);
  v[6] = (short)f2b(f1.z); v[7] = (short)f2b(f1.w);
  *(short8*)(dst + (i - k) + dk) = v;
}

// Poll 64 done-slots (64B-strided) with RELAXED agent loads; no inv, no acquire.
__device__ __forceinline__ void wait_arr2(const int* a0, int t0,
                                          const int* a1, int t1) {
  if (threadIdx.x < 64) {
    for (;;) {
      int v0 = __hip_atomic_load(a0 + threadIdx.x * 16, __ATOMIC_RELAXED,
                                 __HIP_MEMORY_SCOPE_AGENT);
      int v1 = t1;
      if (a1) v1 = __hip_atomic_load(a1 + threadIdx.x * 16, __ATOMIC_RELAXED,
                                     __HIP_MEMORY_SCOPE_AGENT);
      if (__ballot((v0 < t0) || (v1 < t1)) == 0) break;
      __builtin_amdgcn_s_sleep(1);
    }
  }
  __syncthreads();
}

// stage 32 rows x 512 elems via registers (fp32-cvt or bf16 copy), swizzled.
__device__ __forceinline__ void stage_reg512(char* __restrict__ buf, const void* __restrict__ src,
                                             size_t base, size_t stride, bool f32, int tid) {
  #pragma unroll
  for (int i = 0; i < 8; ++i) {
    int g = tid + i * 256;            // 0..2047
    int r = g >> 6, col8 = g & 63;
    short8 v = ld8(src, base + (size_t)r * stride + (size_t)(col8 * 8), f32);
    *(short8*)(buf + r * 1024 + ((col8 * 16) ^ ((r & 7) << 4))) = v;
  }
}

// Fallback ring staging (4-deep rings): RELAXED agent atomic u64 loads.
__device__ __forceinline__ void stage_rows_atomic(char* __restrict__ bufLo,
                                                  char* __restrict__ bufHi,
                                                  const unsigned short* __restrict__ rowbase,
                                                  int tid) {
  const int col = tid * 4;                  // elem col of this thread's u64
  char* d = (col < 512) ? (bufLo + col * 2) : (bufHi + (col - 512) * 2);
  #pragma unroll
  for (int i = 0; i < 32; i += 4) {
    unsigned long long t0[4];
    #pragma unroll
    for (int j = 0; j < 4; ++j)
      t0[j] = __hip_atomic_load(
          (const unsigned long long*)(rowbase + (size_t)(i + j) * 1024) + tid,
          __ATOMIC_RELAXED, __HIP_MEMORY_SCOPE_AGENT);
    #pragma unroll
    for (int j = 0; j < 4; ++j)
      *(unsigned long long*)(d + (i + j) * 1024) = t0[j];
  }
}

// Deep-ring staging: plain async global_load_lds (L1/L2-cacheable; addresses
// are write-once/read-once per launch -> no stale-copy hazard).
__device__ __forceinline__ void stage_rows_deep(char* __restrict__ bufLo,
                                                char* __restrict__ bufHi,
                                                const unsigned short* __restrict__ rowbase,
                                                int wave, int lane) {
  #pragma unroll
  for (int r8 = 0; r8 < 8; ++r8) {
    int r = wave * 8 + r8;
    glds16(rowbase + (size_t)r * 1024 + lane * 8,       bufLo + r * 1024);
    glds16(rowbase + (size_t)r * 1024 + 512 + lane * 8, bufHi + r * 1024);
  }
}

// 16 MFMA steps over one 512-elem chunk; A rows ln / 16+ln, swizzled reads.
#define MFMA_CHUNK(CBASE, BUF, ACC0, ACC1)                                        \
  do { _Pragma("unroll")                                                          \
    for (int s = 0; s < 16; ++s) {                                                \
      int off = (s * 64 + lq * 16) ^ swz;                                         \
      short8 a0 = *(const short8*)((BUF) + ln * 1024 + off);                      \
      short8 a1 = *(const short8*)((BUF) + (16 + ln) * 1024 + off);               \
      ACC0 = __builtin_amdgcn_mfma_f32_16x16x32_bf16(a0, wreg[(CBASE) + s], ACC0, 0, 0, 0); \
      ACC1 = __builtin_amdgcn_mfma_f32_16x16x32_bf16(a1, wreg[(CBASE) + s], ACC1, 0, 0, 0); \
    } } while (0)

__global__ __launch_bounds__(256, 1)
void gru_persist(const void* __restrict__ x,     // [64,512,512]
                 const void* __restrict__ ench,  // [64,1024]
                 const void* __restrict__ Wih0, const void* __restrict__ Whh0,
                 const void* __restrict__ bih0, const void* __restrict__ bhh0,
                 const void* __restrict__ Wih1, const void* __restrict__ Whh1,
                 const void* __restrict__ bih1, const void* __restrict__ bhh1,
                 void* __restrict__ out,         // [64,512,1024] + [64,1024]
                 const unsigned short* __restrict__ wih0s,  // staged bf16 or null
                 const unsigned short* __restrict__ whh0s,
                 const unsigned short* __restrict__ wih1s,
                 const unsigned short* __restrict__ whh1s,
                 const unsigned short* __restrict__ xs,     // pre-swizzled bf16 x or null
                 unsigned short* __restrict__ h0dp,   // deep ring 512x64x1024 or null
                 unsigned short* __restrict__ h1dp,   // deep ring or null
                 int* __restrict__ h0done,       // [2][64][16] ints (64B slots)
                 int* __restrict__ h1done,       // [2][64][16]
                 const int* __restrict__ flag,
                 unsigned short* __restrict__ h0ring,   // 4-deep fallback, swizzled
                 unsigned short* __restrict__ h1ring)
{
  // 64 KB static: buf0 @0, buf1 @32768 (32 rows x 1024B each). FB (8KB gate
  // exchange) aliases buf0 bytes 0..8191 — written only after all MFMAs AND
  // all hp LDS reads of the step are complete.
  __shared__ __align__(16) char smem[65536];
  char* buf0 = smem;
  char* buf1 = smem + 32768;
  float* FB  = (float*)smem;

  const bool f32 = (__hip_atomic_load((int*)flag, __ATOMIC_RELAXED,
                                      __HIP_MEMORY_SCOPE_AGENT) != 0);
  const bool staged = f32 && (wih0s != nullptr);
  const unsigned short* xsw = (f32 && xs) ? xs : nullptr;

  const int tid  = threadIdx.x;
  const int wave = tid >> 6;
  const int lane = tid & 63;
  const int ln   = lane & 15;             // A-row / B-col within 16-tile
  const int lq   = lane >> 4;             // k-quad

  const int wg  = blockIdx.x;
  const bool l0 = (wg < 128);
  const int lw  = l0 ? wg : (wg - 128);
  const int mh  = lw & 1;                 // batch rows 32*mh..+31
  const int jt  = lw >> 1;                // output cols 16*jt..+15

  int* h0d = h0done + mh * 1024;          // this mh's cohort slots (64 x 16 ints)
  int* h1d = h1done + mh * 1024;

  // weight sources
  const void* WI; const void* WH; bool wf32;
  if (staged) { WI = l0 ? (const void*)wih0s : (const void*)wih1s;
                WH = l0 ? (const void*)whh0s : (const void*)whh1s; wf32 = false; }
  else        { WI = l0 ? Wih0 : Wih1; WH = l0 ? Whh0 : Whh1; wf32 = f32; }
  const int KWI = l0 ? 512 : 1024;
  size_t wi_off = 0, wh_off = 0;
  if (wave < 3) {
    int row = wave * 1024 + jt * 16 + ln;   // gate = wave
    wi_off = (size_t)row * KWI;
    wh_off = (size_t)row * 1024;
  }

  // ---- preload ALL weights into registers (L2-state immune) ----
  short8 wreg[64];
  if (wave < 3) {
    if (l0) {
      #pragma unroll
      for (int c = 0; c < 48; ++c) {
        int k = c * 32 + lq * 8;
        wreg[c] = (c < 16) ? ld8(WI, wi_off + k, wf32)
                           : ld8(WH, wh_off + (k - 512), wf32);
      }
    } else {
      #pragma unroll
      for (int c = 0; c < 64; ++c) {
        int k = c * 32 + lq * 8;
        wreg[c] = (c < 32) ? ld8(WI, wi_off + k, wf32)
                           : ld8(WH, wh_off + (k - 1024), wf32);
      }
    }
  }

  // ---- pointwise mapping: thread -> (row rr, col pair cp) ----
  const int cp   = tid & 7;
  const int rr   = tid >> 3;              // 0..31
  const int col0 = jt * 16 + cp * 2;      // even
  const void* bi = l0 ? bih0 : bih1;
  const void* bh = l0 ? bhh0 : bhh1;
  const float bir0 = lds1(bi, col0, f32),        bir1 = lds1(bi, col0 + 1, f32);
  const float bhr0 = lds1(bh, col0, f32),        bhr1 = lds1(bh, col0 + 1, f32);
  const float biz0 = lds1(bi, 1024 + col0, f32), biz1 = lds1(bi, 1025 + col0, f32);
  const float bhz0 = lds1(bh, 1024 + col0, f32), bhz1 = lds1(bh, 1025 + col0, f32);
  const float bin0 = lds1(bi, 2048 + col0, f32), bin1 = lds1(bi, 2049 + col0, f32);
  const float bhn0 = lds1(bh, 2048 + col0, f32), bhn1 = lds1(bh, 2049 + col0, f32);

  const int swz = (ln & 7) << 4;          // byte swizzle for MFMA ds_reads
  const size_t ebase = (size_t)mh * 32 * 1024;   // ench row base (elems)
  const int jj   = col0 & 511;
  const int hpsw = (2 * jj) ^ ((rr & 7) << 4);   // hp pair byte offset in LDS row
  const int brow = mh * 32 + rr;
  const int rsw  = col0 ^ ((brow & 7) << 3);     // pre-swizzled ring col (pair)

  for (int p = 0; p <= 512; ++p) {
    if (l0 && p >= 512) break;
    if (!l0 && p == 0) continue;

    floatx4 accR0 = {0,0,0,0}, accR1 = {0,0,0,0};  // wave0:r wave1:z wave2:n_i
    floatx4 accS0 = {0,0,0,0}, accS1 = {0,0,0,0};  // wave2:n_h
    float hp0, hp1;

    if (l0) {
      // ---- x chunk (k 0..511): private data, cached path ----
      if (xsw) {
        #pragma unroll
        for (int rr8 = 0; rr8 < 8; ++rr8) {
          int r = wave * 8 + rr8;
          glds16(xsw + ((size_t)(mh * 32 + r) * 512 + (size_t)p) * 512 + lane * 8,
                 buf0 + r * 1024);
        }
      } else {
        stage_reg512(buf0, x, (size_t)mh * 32 * 262144 + (size_t)p * 512, 262144, f32, tid);
      }
      __syncthreads();
      if (wave < 3) MFMA_CHUNK(0, buf0, accR0, accR1);
      // deep ring: no WAR backpressure needed (write-once slots)
      if (p >= 1) wait_arr2(h0d, p, (!h0dp && p >= 4) ? h1d : nullptr, p - 3);
      else        __syncthreads();        // protect buf re-stage vs chunk0 reads
      if (p == 0)      { stage_reg512(buf1, ench, ebase,       1024, f32, tid);
                         stage_reg512(buf0, ench, ebase + 512, 1024, f32, tid); }
      else if (h0dp)   stage_rows_deep(buf1, buf0,
                           h0dp + (size_t)(p - 1) * 65536 + (size_t)mh * 32768, wave, lane);
      else             stage_rows_atomic(buf1, buf0,
                           h0ring + (size_t)((p - 1) & 3) * 65536 + (size_t)mh * 32768, tid);
      __syncthreads();
      if (p == 0) {
        hp0 = lds1(ench, (size_t)brow * 1024 + col0, f32);
        hp1 = lds1(ench, (size_t)brow * 1024 + col0 + 1, f32);
      } else {
        const char* hb_ = (col0 < 512) ? buf1 : buf0;
        unsigned int pv = *(const unsigned int*)(hb_ + rr * 1024 + hpsw);
        hp0 = b2f((unsigned short)(pv & 0xFFFFu));
        hp1 = b2f((unsigned short)(pv >> 16));
      }
      if (wave < 2)       { MFMA_CHUNK(16, buf1, accR0, accR1);
                            MFMA_CHUNK(32, buf0, accR0, accR1); }
      else if (wave == 2) { MFMA_CHUNK(16, buf1, accS0, accS1);
                            MFMA_CHUNK(32, buf0, accS0, accS1); }
      __syncthreads();
    } else {
      // ---- h1prev (own-cohort, available early) ----
      wait_arr2(h1d, p - 1, nullptr, 0);
      if (p == 1)      { stage_reg512(buf0, ench, ebase,       1024, f32, tid);
                         stage_reg512(buf1, ench, ebase + 512, 1024, f32, tid); }
      else if (h1dp)   stage_rows_deep(buf0, buf1,
                           h1dp + (size_t)(p - 2) * 65536 + (size_t)mh * 32768, wave, lane);
      else             stage_rows_atomic(buf0, buf1,
                           h1ring + (size_t)((p - 2) & 3) * 65536 + (size_t)mh * 32768, tid);
      __syncthreads();
      if (p == 1) {
        hp0 = lds1(ench, (size_t)brow * 1024 + col0, f32);
        hp1 = lds1(ench, (size_t)brow * 1024 + col0 + 1, f32);
      } else {
        const char* hb_ = (col0 < 512) ? buf0 : buf1;
        unsigned int pv = *(const unsigned int*)(hb_ + rr * 1024 + hpsw);
        hp0 = b2f((unsigned short)(pv & 0xFFFFu));
        hp1 = b2f((unsigned short)(pv >> 16));
      }
      if (wave < 2)       { MFMA_CHUNK(32, buf0, accR0, accR1);
                            MFMA_CHUNK(48, buf1, accR0, accR1); }
      else if (wave == 2) { MFMA_CHUNK(32, buf0, accS0, accS1);
                            MFMA_CHUNK(48, buf1, accS0, accS1); }
      // ---- h0cur (fresh dependency); wait contains the guarding barrier ----
      wait_arr2(h0d, p, nullptr, 0);
      if (h0dp) stage_rows_deep(buf0, buf1,
                    h0dp + (size_t)(p - 1) * 65536 + (size_t)mh * 32768, wave, lane);
      else      stage_rows_atomic(buf0, buf1,
                    h0ring + (size_t)((p - 1) & 3) * 65536 + (size_t)mh * 32768, tid);
      __syncthreads();
      if (wave < 3) { MFMA_CHUNK(0,  buf0, accR0, accR1);
                      MFMA_CHUNK(16, buf1, accR0, accR1); }
      __syncthreads();
    }

    // ---- cross-wave gate exchange (FB aliases buf0; all MFMAs + hp reads done) ----
    if (wave < 3) {
      #pragma unroll
      for (int i = 0; i < 4; ++i) {
        int row0 = lq * 4 + i;                      // C/D: row=quad*4+reg, col=ln
        FB[wave * 512 +  row0       * 16 + ln] = accR0[i];
        FB[wave * 512 + (16 + row0) * 16 + ln] = accR1[i];
        if (wave == 2) {
          FB[3 * 512 +  row0       * 16 + ln] = accS0[i];
          FB[3 * 512 + (16 + row0) * 16 + ln] = accS1[i];
        }
      }
    }
    __syncthreads();

    // ---- fused GRU pointwise + publish (1 col-pair/thread, 32 rows) ----
    {
      int fbb = rr * 16 + cp * 2;
      float sr0  = FB[fbb],        sr1  = FB[fbb + 1];
      float sz0  = FB[512 + fbb],  sz1  = FB[513 + fbb];
      float sni0 = FB[1024 + fbb], sni1 = FB[1025 + fbb];
      float snh0 = FB[1536 + fbb], snh1 = FB[1537 + fbb];
      float rg0 = 1.f / (1.f + __expf(-(sr0 + bir0 + bhr0)));
      float rg1 = 1.f / (1.f + __expf(-(sr1 + bir1 + bhr1)));
      float zg0 = 1.f / (1.f + __expf(-(sz0 + biz0 + bhz0)));
      float zg1 = 1.f / (1.f + __expf(-(sz1 + biz1 + bhz1)));
      float ng0 = tanhf(sni0 + bin0 + rg0 * (snh0 + bhn0));   // r*(hn + bhh_n) !
      float ng1 = tanhf(sni1 + bin1 + rg1 * (snh1 + bhn1));
      float hnew0 = (1.f - zg0) * ng0 + zg0 * hp0;
      float hnew1 = (1.f - zg1) * ng1 + zg1 * hp1;
      unsigned int pair = (unsigned int)f2b(hnew0) | ((unsigned int)f2b(hnew1) << 16);
      if (l0) {
        unsigned int* rdst = h0dp
          ? (unsigned int*)(h0dp + (size_t)p * 65536 + (size_t)brow * 1024 + rsw)
          : (unsigned int*)(h0ring + (size_t)(p & 3) * 65536 + (size_t)brow * 1024 + rsw);
        __hip_atomic_store(rdst, pair, __ATOMIC_RELAXED, __HIP_MEMORY_SCOPE_AGENT);
      } else {
        size_t oidx = ((size_t)brow * 512 + (size_t)(p - 1)) * 1024 + col0;
        if (f32) { float2 o2 = {hnew0, hnew1}; *(float2*)((float*)out + oidx) = o2; }
        else     *(unsigned int*)((unsigned short*)out + oidx) = pair;
        unsigned int* rdst = h1dp
          ? (unsigned int*)(h1dp + (size_t)(p - 1) * 65536 + (size_t)brow * 1024 + rsw)
          : (unsigned int*)(h1ring + (size_t)((p - 1) & 3) * 65536 + (size_t)brow * 1024 + rsw);
        __hip_atomic_store(rdst, pair, __ATOMIC_RELAXED, __HIP_MEMORY_SCOPE_AGENT);
        if (p == 512) {
          size_t cidx = 33554432u + (size_t)brow * 1024 + col0;   // final carry h1
          if (f32) { ((float*)out)[cidx] = hnew0; ((float*)out)[cidx + 1] = hnew1; }
          else     *(unsigned int*)((unsigned short*)out + cidx) = pair;
        }
      }
    }

    // ---- publish: barrier drains vmcnt (sc1 stores at coherence point),
    //      then one relaxed flag store. No wbl2, no inv. ----
    __syncthreads();
    if (tid == 0) {
      if (l0) __hip_atomic_store(&h0d[jt * 16], p + 1, __ATOMIC_RELAXED,
                                 __HIP_MEMORY_SCOPE_AGENT);
      else    __hip_atomic_store(&h1d[jt * 16], p, __ATOMIC_RELAXED,
                                 __HIP_MEMORY_SCOPE_AGENT);
    }
  }
}

extern "C" void kernel_launch(void* const* d_in, const int* in_sizes, int n_in,
                              void* d_out, int out_size, void* d_ws, size_t ws_size,
                              hipStream_t stream) {
  char* ws = (char*)d_ws;
  int* h0done = (int*)ws;                              // [2][64][16] = 8192 B
  int* h1done = (int*)(ws + 8192);                     // [2][64][16] = 8192 B
  int* flag   = (int*)(ws + 16384);
  unsigned short* h0ring = (unsigned short*)(ws + 32768);    // 512 KB (fallback)
  unsigned short* h1ring = (unsigned short*)(ws + 557056);   // 512 KB (fallback)

  // staged bf16 weights (only if ws fits): 22 MB starting at 1,081,344
  const size_t W0 = 1081344;
  unsigned short *w0s = nullptr, *w1s = nullptr, *w2s = nullptr, *w3s = nullptr;
  bool fits = ws_size >= (W0 + 22020096);
  if (fits) {
    w0s = (unsigned short*)(ws + W0);                 // Wih0b: 3,145,728 B
    w1s = (unsigned short*)(ws + W0 + 3145728);       // Whh0b: 6,291,456 B
    w2s = (unsigned short*)(ws + W0 + 9437184);       // Wih1b: 6,291,456 B
    w3s = (unsigned short*)(ws + W0 + 15728640);      // Whh1b: 6,291,456 B
  }
  // pre-swizzled bf16 x (33.5 MB) if ws also fits that
  const size_t XS0 = W0 + 22020096;                   // 23,101,440
  unsigned short* xsw = nullptr;
  bool fits_x = fits && (ws_size >= XS0 + 33554432);
  if (fits_x) xsw = (unsigned short*)(ws + XS0);

  // full-depth (write-once) rings: 64 MB each
  const size_t D0 = XS0 + 33554432;                   // 56,655,872
  const size_t DRING = (size_t)512 * 65536 * 2;       // 67,108,864 B
  unsigned short *h0dp = nullptr, *h1dp = nullptr;
  if (fits_x && ws_size >= D0 + DRING)          h0dp = (unsigned short*)(ws + D0);
  if (fits_x && ws_size >= D0 + 2 * DRING)      h1dp = (unsigned short*)(ws + D0 + DRING);

  hipMemsetAsync(d_ws, 0, 20480, stream);             // done slots + flag

  hipLaunchKernelGGL(detect_mode, dim3(1), dim3(256), 0, stream,
                     (const unsigned int*)d_in[3], flag);
  if (fits) {
    hipLaunchKernelGGL(cvt_w, dim3(256), dim3(256), 0, stream,
                       (const float*)d_in[3], w0s, 1572864, flag);
    hipLaunchKernelGGL(cvt_w, dim3(256), dim3(256), 0, stream,
                       (const float*)d_in[4], w1s, 3145728, flag);
    hipLaunchKernelGGL(cvt_w, dim3(256), dim3(256), 0, stream,
                       (const float*)d_in[7], w2s, 3145728, flag);
    hipLaunchKernelGGL(cvt_w, dim3(256), dim3(256), 0, stream,
                       (const float*)d_in[8], w3s, 3145728, flag);
  }
  if (fits_x) {
    hipLaunchKernelGGL(cvt_x, dim3(8192), dim3(256), 0, stream,
                       (const float*)d_in[0], xsw, flag);
  }

  hipLaunchKernelGGL(gru_persist, dim3(256), dim3(256), 0, stream,
                     d_in[0], d_in[2],
                     d_in[3], d_in[4], d_in[5], d_in[6],
                     d_in[7], d_in[8], d_in[9], d_in[10],
                     d_out, w0s, w1s, w2s, w3s, xsw, h0dp, h1dp,
                     h0done, h1done, flag, h0ring, h1ring);
}